// Round 9
// baseline (268.506 us; speedup 1.0000x reference)
//
#include <hip/hip_runtime.h>
#include <hip/hip_bf16.h>
#include <math.h>

#define Bsz 2
#define Tt  2048
#define Cc  1024
#define Hh  16
#define Dd  64

typedef __attribute__((ext_vector_type(8))) short short8v;
typedef __attribute__((ext_vector_type(4))) short short4v;
typedef __attribute__((ext_vector_type(4))) float f32x4;
typedef __attribute__((ext_vector_type(16))) float f32x16;
typedef __attribute__((ext_vector_type(4))) unsigned int uint4v;

static __device__ __forceinline__ short f2bf(float f) {
  __hip_bfloat16 h = __float2bfloat16(f);
  return __builtin_bit_cast(short, h);
}
static __device__ __forceinline__ float bf2f(short s) {
  unsigned u = ((unsigned)(unsigned short)s) << 16;
  return __builtin_bit_cast(float, u);
}
static __device__ __forceinline__ void gll16(const void* g, void* l) {
  __builtin_amdgcn_global_load_lds((const __attribute__((address_space(1))) unsigned int*)g,
                                   (__attribute__((address_space(3))) unsigned int*)l, 16, 0, 0);
}

// ---------------- prepass: split x into bf16 hi/lo ----------------
__global__ void split_x(const float* __restrict__ x, short* __restrict__ xhi,
                        short* __restrict__ xlo) {
  int t = blockIdx.x * 256 + threadIdx.x;
  const float* s = x + (size_t)t * 8;
  float4 a = *(const float4*)s, b = *(const float4*)(s + 4);
  float vv[8] = {a.x, a.y, a.z, a.w, b.x, b.y, b.z, b.w};
  short8v h, l;
#pragma unroll
  for (int e = 0; e < 8; ++e) {
    short hb = f2bf(vv[e]);
    h[e] = hb;
    l[e] = f2bf(vv[e] - bf2f(hb));
  }
  *(short8v*)(xhi + (size_t)t * 8) = h;
  *(short8v*)(xlo + (size_t)t * 8) = l;
}

// ---------------- prepass: split + transpose W -> Wt[n][k] hi/lo ----------------
__global__ __launch_bounds__(256) void split_wT(const float* __restrict__ Wq,
                                                const float* __restrict__ Wk,
                                                const float* __restrict__ Wv,
                                                const float* __restrict__ Wo,
                                                short* __restrict__ WT) {
  __shared__ float T[64][68];
  const int z = blockIdx.z;
  const float* W = z == 0 ? Wq : z == 1 ? Wk : z == 2 ? Wv : Wo;
  short* oh = WT + (size_t)z * 2097152;
  short* ol = oh + 1048576;
  const int n0 = blockIdx.x * 64, k0 = blockIdx.y * 64;
  const int tid = threadIdx.x;
#pragma unroll
  for (int i = 0; i < 4; ++i) {
    int slot = tid + i * 256;
    int r = slot >> 4, c4 = (slot & 15) << 2;
    *(float4*)&T[r][c4] = *(const float4*)(W + (size_t)(k0 + r) * Cc + n0 + c4);
  }
  __syncthreads();
#pragma unroll
  for (int i = 0; i < 2; ++i) {
    int slot = tid + i * 256;
    int nl = slot >> 3, ks = (slot & 7) << 3;
    short8v h, l;
#pragma unroll
    for (int e = 0; e < 8; ++e) {
      float v = T[ks + e][nl];
      short hb = f2bf(v);
      h[e] = hb;
      l[e] = f2bf(v - bf2f(hb));
    }
    *(short8v*)(oh + (size_t)(n0 + nl) * Cc + k0 + ks) = h;
    *(short8v*)(ol + (size_t)(n0 + nl) * Cc + k0 + ks) = l;
  }
}

// ================= 128x128 split-bf16 GEMM core =================
__device__ __forceinline__ void core128(const short* __restrict__ Ah, const short* __restrict__ Al,
                                        const short* __restrict__ Bh, const short* __restrict__ Bl,
                                        short* AhiL, short* AloL, short* BhiL, short* BloL,
                                        int row0, int col0, int wv, int lane, f32x4 acc[4][4]) {
  const int l15 = lane & 15, g = lane >> 4;
  const int wr = wv >> 1, wc = wv & 1;

  const int srow0 = wv * 32 + (lane >> 2);
  const int srow1 = srow0 + 16;
  const int sch0 = ((lane & 3) ^ ((lane >> 2) & 3)) << 3;
  const size_t aoff0 = (size_t)(row0 + srow0) * Cc + sch0;
  const size_t aoff1 = (size_t)(row0 + srow1) * Cc + sch0;
  const size_t boff0 = (size_t)(col0 + srow0) * Cc + sch0;
  const size_t boff1 = (size_t)(col0 + srow1) * Cc + sch0;
  short* dA0 = AhiL + wv * 1024;  short* dA1 = dA0 + 512;
  short* dAl0 = AloL + wv * 1024; short* dAl1 = dAl0 + 512;
  short* dB0 = BhiL + wv * 1024;  short* dB1 = dB0 + 512;
  short* dBl0 = BloL + wv * 1024; short* dBl1 = dBl0 + 512;

  int aL[4], bL[4];
#pragma unroll
  for (int m = 0; m < 4; ++m) aL[m] = (wr * 64 + m * 16 + l15) * 32 + ((g ^ (l15 & 3)) << 3);
#pragma unroll
  for (int n = 0; n < 4; ++n) bL[n] = (wc * 64 + n * 16 + l15) * 32 + ((g ^ (l15 & 3)) << 3);

  for (int k0 = 0; k0 < Cc; k0 += 32) {
    __syncthreads();
    gll16(Ah + aoff0 + k0, dA0);
    gll16(Ah + aoff1 + k0, dA1);
    gll16(Al + aoff0 + k0, dAl0);
    gll16(Al + aoff1 + k0, dAl1);
    gll16(Bh + boff0 + k0, dB0);
    gll16(Bh + boff1 + k0, dB1);
    gll16(Bl + boff0 + k0, dBl0);
    gll16(Bl + boff1 + k0, dBl1);
    __syncthreads();
    short8v ah[4], al[4], bh[4], bl[4];
#pragma unroll
    for (int m = 0; m < 4; ++m) {
      ah[m] = *(short8v*)&AhiL[aL[m]];
      al[m] = *(short8v*)&AloL[aL[m]];
    }
#pragma unroll
    for (int n = 0; n < 4; ++n) {
      bh[n] = *(short8v*)&BhiL[bL[n]];
      bl[n] = *(short8v*)&BloL[bL[n]];
    }
#pragma unroll
    for (int m = 0; m < 4; ++m)
#pragma unroll
      for (int n = 0; n < 4; ++n) {
        acc[m][n] = __builtin_amdgcn_mfma_f32_16x16x32_bf16(ah[m], bh[n], acc[m][n], 0, 0, 0);
        acc[m][n] = __builtin_amdgcn_mfma_f32_16x16x32_bf16(ah[m], bl[n], acc[m][n], 0, 0, 0);
        acc[m][n] = __builtin_amdgcn_mfma_f32_16x16x32_bf16(al[m], bh[n], acc[m][n], 0, 0, 0);
      }
  }
}

// ---------------- QKV projection GEMM ----------------
__global__ __launch_bounds__(256, 3) void gemm_qkv(const short* __restrict__ xhi,
                                                   const short* __restrict__ xlo,
                                                   const short* __restrict__ WT,
                                                   const float* __restrict__ bq,
                                                   const float* __restrict__ bk,
                                                   const float* __restrict__ bv,
                                                   short* __restrict__ qb,
                                                   short* __restrict__ kb,
                                                   short* __restrict__ vb) {
  __shared__ short AhiL[4096], AloL[4096], BhiL[4096], BloL[4096];
  const int mode = blockIdx.y;
  const short* Bh = WT + (size_t)mode * 2097152;
  const short* Bl = Bh + 1048576;
  const float* bias = mode == 0 ? bq : mode == 1 ? bk : bv;
  short* Y = mode == 0 ? qb : mode == 1 ? kb : vb;

  const int bid = blockIdx.x;
  const int nid = ((bid & 7) << 5) | (bid >> 3);
  const int row0 = (nid >> 3) * 128, col0 = (nid & 7) * 128;
  const int lane = threadIdx.x & 63, wv = threadIdx.x >> 6;
  const int l15 = lane & 15, g = lane >> 4;
  const int wr = wv >> 1, wc = wv & 1;

  f32x4 acc[4][4];
#pragma unroll
  for (int m = 0; m < 4; ++m)
#pragma unroll
    for (int n = 0; n < 4; ++n) acc[m][n] = (f32x4){0.f, 0.f, 0.f, 0.f};

  core128(xhi, xlo, Bh, Bl, AhiL, AloL, BhiL, BloL, row0, col0, wv, lane, acc);

  const int cbase = col0 + wc * 64;
  const int h = cbase >> 6;
  if (mode < 2) {
    const float scale = (mode == 0) ? 0.18033688f : 1.0f;   // 1/8 * log2(e) folded for Q
#pragma unroll
    for (int n = 0; n < 2; ++n) {
      const int d = n * 16 + l15;
      const float b0 = bias[cbase + d], b1 = bias[cbase + d + 32];
      const float inv = exp2f(-(float)d * (13.2877123795494f / 32.f));
#pragma unroll
      for (int m = 0; m < 4; ++m)
#pragma unroll
        for (int rr = 0; rr < 4; ++rr) {
          int R = row0 + wr * 64 + m * 16 + g * 4 + rr;
          int bI = R >> 11, t = R & (Tt - 1);
          float sn, cs;
          sincosf((float)t * inv, &sn, &cs);
          float v0 = acc[m][n][rr] + b0, v1 = acc[m][n + 2][rr] + b1;
          size_t base = (((size_t)(bI * Hh + h) * Tt + t) << 6) + d;
          Y[base]      = f2bf((v0 * cs - v1 * sn) * scale);
          Y[base + 32] = f2bf((v1 * cs + v0 * sn) * scale);
        }
    }
  } else {
    // V: write transposed [B,H,D,T]; rr gives consecutive t -> 8B stores
#pragma unroll
    for (int n = 0; n < 2; ++n) {
      const int d = n * 16 + l15;
      const float b0 = bias[cbase + d], b1 = bias[cbase + d + 32];
#pragma unroll
      for (int m = 0; m < 4; ++m) {
        int R = row0 + wr * 64 + m * 16 + g * 4;
        int bI = R >> 11, t = R & (Tt - 1);
        short4v s0, s1;
#pragma unroll
        for (int rr = 0; rr < 4; ++rr) {
          s0[rr] = f2bf(acc[m][n][rr] + b0);
          s1[rr] = f2bf(acc[m][n + 2][rr] + b1);
        }
        size_t base = ((size_t)(bI * Hh + h) * Dd);
        *(short4v*)(Y + (base + d) * Tt + t)      = s0;
        *(short4v*)(Y + (base + d + 32) * Tt + t) = s1;
      }
    }
  }
}

// ---------------- final output GEMM (128x128 tile, fp32 out) ----------------
__global__ __launch_bounds__(256, 3) void gemm_out(const short* __restrict__ ahi,
                                                   const short* __restrict__ alo,
                                                   const short* __restrict__ WTo,
                                                   const float* __restrict__ bias,
                                                   float* __restrict__ Y) {
  __shared__ short AhiL[4096], AloL[4096], BhiL[4096], BloL[4096];
  const short* Bh = WTo;
  const short* Bl = WTo + 1048576;

  const int bid = blockIdx.x;
  const int nid = ((bid & 7) << 5) | (bid >> 3);
  const int row0 = (nid >> 3) * 128, col0 = (nid & 7) * 128;
  const int lane = threadIdx.x & 63, wv = threadIdx.x >> 6;
  const int l15 = lane & 15, g = lane >> 4;
  const int wr = wv >> 1, wc = wv & 1;

  f32x4 acc[4][4];
#pragma unroll
  for (int m = 0; m < 4; ++m)
#pragma unroll
    for (int n = 0; n < 4; ++n) acc[m][n] = (f32x4){0.f, 0.f, 0.f, 0.f};

  core128(ahi, alo, Bh, Bl, AhiL, AloL, BhiL, BloL, row0, col0, wv, lane, acc);

  const int cbase = col0 + wc * 64;
#pragma unroll
  for (int n = 0; n < 2; ++n) {
    const int ccol = cbase + n * 16 + l15;
    const float b0 = bias[ccol], b1 = bias[ccol + 32];
#pragma unroll
    for (int m = 0; m < 4; ++m)
#pragma unroll
      for (int rr = 0; rr < 4; ++rr) {
        int R = row0 + wr * 64 + m * 16 + g * 4 + rr;
        Y[(size_t)R * Cc + ccol]      = acc[m][n][rr] + b0;
        Y[(size_t)R * Cc + ccol + 32] = acc[m][n + 2][rr] + b1;
      }
  }
}

// ================= MFMA flash attention v6: split-K + K reg-prefetch =================
// As round 8 (split-K 2 halves, LDS-free) PLUS:
//  - K fragments for chunk c+1 prefetched into a ping-pong register set while
//    chunk c computes (K-load latency gets a full chunk of slack).
//  - P-pack via v_cvt_pk_bf16_f32 (1 op per bf16 pair instead of RNE sequence).
__device__ __forceinline__ void attn_chunk(
    int jt, int qbase, int tq, int hb,
    const short* __restrict__ vtb,
    const short8v& kf0, const short8v& kf1, const short8v& kf2, const short8v& kf3,
    const short8v qf[4], float& mrun, float& lrun, f32x16 oacc[2]) {
  // V fragments issued first: ~full softmax duration of slack before PV
  const short* vr0 = vtb + jt;
  const short* vr1 = vtb + 32 * Tt + jt;
  short8v v00 = *(const short8v*)(vr0);
  short8v v01 = *(const short8v*)(vr0 + 16);
  short8v v10 = *(const short8v*)(vr1);
  short8v v11 = *(const short8v*)(vr1 + 16);

  f32x16 se;
#pragma unroll
  for (int r = 0; r < 16; ++r) se[r] = 0.f;
  se = __builtin_amdgcn_mfma_f32_32x32x16_bf16(kf0, qf[0], se, 0, 0, 0);
  se = __builtin_amdgcn_mfma_f32_32x32x16_bf16(kf1, qf[1], se, 0, 0, 0);
  se = __builtin_amdgcn_mfma_f32_32x32x16_bf16(kf2, qf[2], se, 0, 0, 0);
  se = __builtin_amdgcn_mfma_f32_32x32x16_bf16(kf3, qf[3], se, 0, 0, 0);

  if (jt < qbase - 480) {   // boundary chunk: window mask
    int th = tq - 511 - jt;
#pragma unroll
    for (int r = 0; r < 16; ++r) {
      int row = (r & 3) + 8 * (r >> 2) + 4 * hb;
      if (row < th) se[r] = -1e30f;
    }
  }

  // tree max
  float x0 = fmaxf(se[0], se[1]),   x1 = fmaxf(se[2], se[3]);
  float x2 = fmaxf(se[4], se[5]),   x3 = fmaxf(se[6], se[7]);
  float x4 = fmaxf(se[8], se[9]),   x5 = fmaxf(se[10], se[11]);
  float x6 = fmaxf(se[12], se[13]), x7 = fmaxf(se[14], se[15]);
  x0 = fmaxf(x0, x1); x2 = fmaxf(x2, x3); x4 = fmaxf(x4, x5); x6 = fmaxf(x6, x7);
  float cmax = fmaxf(fmaxf(x0, x2), fmaxf(x4, x6));
  cmax = fmaxf(cmax, __shfl_xor(cmax, 32));

  if (!__all(cmax <= mrun + 8.0f)) {
    float mnew = fmaxf(fmaxf(mrun, cmax), -1e29f);
    float fac = exp2f(mrun - mnew);
    lrun *= fac;
#pragma unroll
    for (int t = 0; t < 2; ++t)
#pragma unroll
      for (int r = 0; r < 16; ++r) oacc[t][r] *= fac;
    mrun = mnew;
  }

  float p[16], psum = 0.f;
#pragma unroll
  for (int r = 0; r < 16; ++r) { p[r] = exp2f(se[r] - mrun); psum += p[r]; }
  psum += __shfl_xor(psum, 32);
  lrun += psum;

  // pack p pairs with HW cvt_pk; exchange across half-waves
  unsigned pk[8], pw[8];
#pragma unroll
  for (int i = 0; i < 8; ++i) {
    asm("v_cvt_pk_bf16_f32 %0, %1, %2" : "=v"(pk[i]) : "v"(p[2 * i]), "v"(p[2 * i + 1]));
  }
#pragma unroll
  for (int i = 0; i < 8; ++i) pw[i] = __shfl_xor(pk[i], 32);

  uint4v f0, f1;
  f0[0] = hb ? pw[2] : pk[0];
  f0[1] = hb ? pw[3] : pk[1];
  f0[2] = hb ? pk[2] : pw[0];
  f0[3] = hb ? pk[3] : pw[1];
  f1[0] = hb ? pw[6] : pk[4];
  f1[1] = hb ? pw[7] : pk[5];
  f1[2] = hb ? pk[6] : pw[4];
  f1[3] = hb ? pk[7] : pw[5];
  short8v pf0 = __builtin_bit_cast(short8v, f0);
  short8v pf1 = __builtin_bit_cast(short8v, f1);

  oacc[0] = __builtin_amdgcn_mfma_f32_32x32x16_bf16(v00, pf0, oacc[0], 0, 0, 0);
  oacc[0] = __builtin_amdgcn_mfma_f32_32x32x16_bf16(v01, pf1, oacc[0], 0, 0, 0);
  oacc[1] = __builtin_amdgcn_mfma_f32_32x32x16_bf16(v10, pf0, oacc[1], 0, 0, 0);
  oacc[1] = __builtin_amdgcn_mfma_f32_32x32x16_bf16(v11, pf1, oacc[1], 0, 0, 0);
}

#define LOADK(JT, K0, K1, K2, K3)                        \
  {                                                      \
    const short* kr_ = kgb + (size_t)(JT) * Dd;          \
    K0 = *(const short8v*)(kr_);                         \
    K1 = *(const short8v*)(kr_ + 16);                    \
    K2 = *(const short8v*)(kr_ + 32);                    \
    K3 = *(const short8v*)(kr_ + 48);                    \
  }

__global__ __launch_bounds__(256, 4) void attn_mfma(const short* __restrict__ q,
                                                    const short* __restrict__ k,
                                                    const short* __restrict__ vT,
                                                    short* __restrict__ ohi,
                                                    short* __restrict__ olo,
                                                    float* __restrict__ yb,
                                                    float* __restrict__ side) {
  const int n = blockIdx.x;           // 1024
  const int xcd = n & 7;
  const int s7 = n >> 3;              // 0..127
  const int kh = s7 >> 6;             // key-half
  const int slot = s7 & 63;
  const int cu = slot & 31, jj = slot >> 5;
  const int bhj = (jj ? 2 : 0) + (cu >> 4);
  const int Q = jj ? (15 - (cu & 15)) : (cu & 15);
  const int bh = xcd * 4 + bhj;
  const int q0 = Q * 128;

  const int tid = threadIdx.x;
  const int lane = tid & 63;
  const int wv = tid >> 6;
  const int l31 = lane & 31;
  const int hb = lane >> 5;           // half-wave
  const int qbase = q0 + wv * 32;
  const int tq = qbase + l31;

  const short* qgb = q + (size_t)bh * Tt * Dd;
  const short* kgb = k + (size_t)bh * Tt * Dd + (size_t)l31 * Dd + 8 * hb;
  const short* vtb = vT + (size_t)bh * Dd * Tt + (size_t)l31 * Tt + 8 * hb;

  // Q fragments: MFMA i covers dims 16i + 8hb .. +7 (scale*log2e folded)
  const short* qp = qgb + (size_t)tq * Dd + 8 * hb;
  short8v qf[4];
#pragma unroll
  for (int i = 0; i < 4; ++i) qf[i] = *(const short8v*)(qp + 16 * i);

  f32x16 oacc[2];
#pragma unroll
  for (int t = 0; t < 2; ++t)
#pragma unroll
    for (int r = 0; r < 16; ++r) oacc[t][r] = 0.f;
  float mrun = -1e30f, lrun = 0.f;

  const int ws0 = (qbase - 511) > 0 ? (qbase - 511) : 0;
  const int wstart = ws0 & ~31;
  const int nch = (Tt - wstart) >> 5;
  const int lower = (nch + 1) >> 1;
  const int mystart = wstart + (kh ? (lower << 5) : 0);
  const int myn = kh ? (nch - lower) : lower;

  // ---- K ping-pong prefetch ----
  short8v kA0, kA1, kA2, kA3, kB0, kB1, kB2, kB3;
  LOADK(mystart, kA0, kA1, kA2, kA3);

  int c = 0;
  for (; c + 1 < myn; c += 2) {
    const int jt0 = mystart + (c << 5);
    LOADK(jt0 + 32, kB0, kB1, kB2, kB3);                     // prefetch c+1
    attn_chunk(jt0, qbase, tq, hb, vtb, kA0, kA1, kA2, kA3, qf, mrun, lrun, oacc);
    if (c + 2 < myn) LOADK(jt0 + 64, kA0, kA1, kA2, kA3);    // prefetch c+2
    attn_chunk(jt0 + 32, qbase, tq, hb, vtb, kB0, kB1, kB2, kB3, qf, mrun, lrun, oacc);
  }
  if (c < myn) {
    attn_chunk(mystart + (c << 5), qbase, tq, hb, vtb, kA0, kA1, kA2, kA3, qf, mrun, lrun, oacc);
  }

  // ---- epilogue ----
  const float invl = 1.f / lrun;
  const int row = bh * Tt + tq;
  if (hb == 0) {
    side[(kh << 17) + row]         = mrun;
    side[(kh << 17) + 65536 + row] = lrun;
  }
  const int bI = bh >> 4, hd = bh & 15;
  if (kh == 0) {
    short* oh = ohi + ((size_t)(bI * Tt + tq)) * Cc + hd * Dd;
    short* ol = olo + ((size_t)(bI * Tt + tq)) * Cc + hd * Dd;
#pragma unroll
    for (int t = 0; t < 2; ++t)
#pragma unroll
      for (int rq = 0; rq < 4; ++rq) {
        short4v hv, lv;
#pragma unroll
        for (int rr = 0; rr < 4; ++rr) {
          float val = oacc[t][4 * rq + rr] * invl;
          short hbv = f2bf(val);
          hv[rr] = hbv;
          lv[rr] = f2bf(val - bf2f(hbv));
        }
        int d0 = 32 * t + 8 * rq + 4 * hb;
        *(short4v*)(oh + d0) = hv;
        *(short4v*)(ol + d0) = lv;
      }
  } else {
    float* yp = yb + (size_t)row * 64;
#pragma unroll
    for (int t = 0; t < 2; ++t)
#pragma unroll
      for (int rq = 0; rq < 4; ++rq) {
        f32x4 o4;
#pragma unroll
        for (int rr = 0; rr < 4; ++rr) o4[rr] = oacc[t][4 * rq + rr] * invl;
        *(f32x4*)(yp + 32 * t + 8 * rq + 4 * hb) = o4;
      }
  }
}

// ---------------- merge the two key-halves (in place on ohi/olo) ----------------
__global__ __launch_bounds__(256) void attn_merge(short* __restrict__ ohi,
                                                  short* __restrict__ olo,
                                                  const float* __restrict__ yb,
                                                  const float* __restrict__ side) {
  const int gt = blockIdx.x * 256 + threadIdx.x;   // 262144
  const int row = gt >> 2;
  const int qd = (gt & 3) << 4;
  const float m0 = side[row],          l0 = side[65536 + row];
  const float m1 = side[131072 + row], l1 = side[196608 + row];
  const float m = fmaxf(m0, m1);
  const float w0 = exp2f(m0 - m) * l0;
  const float w1 = exp2f(m1 - m) * l1;
  const float inv = 1.f / (w0 + w1);
  const float a0 = w0 * inv, a1 = w1 * inv;

  const int bh = row >> 11, tq = row & 2047;
  const int bI = bh >> 4, hd = bh & 15;
  short* oh = ohi + ((size_t)(bI * Tt + tq)) * Cc + hd * Dd + qd;
  short* ol = olo + ((size_t)(bI * Tt + tq)) * Cc + hd * Dd + qd;
  const float* yp = yb + (size_t)row * 64 + qd;

  short8v h0 = *(short8v*)oh,  h1 = *(short8v*)(oh + 8);
  short8v g0 = *(short8v*)ol,  g1 = *(short8v*)(ol + 8);
  short8v nh0, nh1, ng0, ng1;
#pragma unroll
  for (int e = 0; e < 8; ++e) {
    float o = a0 * (bf2f(h0[e]) + bf2f(g0[e])) + a1 * yp[e];
    short hv = f2bf(o);
    nh0[e] = hv;
    ng0[e] = f2bf(o - bf2f(hv));
  }
#pragma unroll
  for (int e = 0; e < 8; ++e) {
    float o = a0 * (bf2f(h1[e]) + bf2f(g1[e])) + a1 * yp[8 + e];
    short hv = f2bf(o);
    nh1[e] = hv;
    ng1[e] = f2bf(o - bf2f(hv));
  }
  *(short8v*)oh = nh0;
  *(short8v*)(oh + 8) = nh1;
  *(short8v*)ol = ng0;
  *(short8v*)(ol + 8) = ng1;
}

extern "C" void kernel_launch(void* const* d_in, const int* in_sizes, int n_in,
                              void* d_out, int out_size, void* d_ws, size_t ws_size,
                              hipStream_t stream) {
  const float* x  = (const float*)d_in[0];
  const float* Wq = (const float*)d_in[1];
  const float* bq = (const float*)d_in[2];
  const float* Wk = (const float*)d_in[3];
  const float* bk = (const float*)d_in[4];
  const float* Wv = (const float*)d_in[5];
  const float* bv = (const float*)d_in[6];
  const float* Wo = (const float*)d_in[7];
  const float* bo = (const float*)d_in[8];

  short* ws16 = (short*)d_ws;
  short* xhi = ws16;                  // 8MB; reused as attn_hi (half 0) after projections
  short* xlo = ws16 + 4194304;        // 8MB; reused as attn_lo (half 0)
  short* WT  = ws16 + 8388608;        // 16MB
  short* qb  = ws16 + 16777216;       // 8MB bf16 [B,H,T,D]
  short* kb  = ws16 + 20971520;       // 8MB bf16 [B,H,T,D]
  short* vb  = ws16 + 25165824;       // 8MB bf16 [B,H,D,T]  (V transposed)
  float* yb   = (float*)(ws16 + 29360128);  // 16.78MB fp32 half-1 partial O [65536][64]
  float* side = yb + 4194304;               // 1MB: [kh][m|l][65536]

  split_x<<<2048, 256, 0, stream>>>(x, xhi, xlo);
  split_wT<<<dim3(16, 16, 4), 256, 0, stream>>>(Wq, Wk, Wv, Wo, WT);

  gemm_qkv<<<dim3(256, 3), 256, 0, stream>>>(xhi, xlo, WT, bq, bk, bv, qb, kb, vb);

  attn_mfma<<<1024, 256, 0, stream>>>(qb, kb, vb, xhi, xlo, yb, side);
  attn_merge<<<1024, 256, 0, stream>>>(xhi, xlo, yb, side);

  gemm_out<<<256, 256, 0, stream>>>(xhi, xlo, WT + 6 * 1048576, bo, (float*)d_out);
}

// Round 10
// 145.963 us; speedup vs baseline: 1.8395x; 1.8395x over previous
//
#include <hip/hip_runtime.h>
#include <hip/hip_bf16.h>
#include <math.h>

#define Bsz 2
#define Tt  2048
#define Cc  1024
#define Hh  16
#define Dd  64

typedef __attribute__((ext_vector_type(8))) short short8v;
typedef __attribute__((ext_vector_type(4))) short short4v;
typedef __attribute__((ext_vector_type(8))) _Float16 half8v;
typedef __attribute__((ext_vector_type(2))) _Float16 h2v;
typedef __attribute__((ext_vector_type(4))) float f32x4;
typedef __attribute__((ext_vector_type(16))) float f32x16;
typedef __attribute__((ext_vector_type(4))) unsigned int uint4v;

static __device__ __forceinline__ short f2h(float f) {
  _Float16 h = (_Float16)f;   // v_cvt_f16_f32 (RNE)
  return __builtin_bit_cast(short, h);
}
static __device__ __forceinline__ float h2f(short s) {
  _Float16 h = __builtin_bit_cast(_Float16, s);
  return (float)h;
}
static __device__ __forceinline__ void gll16(const void* g, void* l) {
  __builtin_amdgcn_global_load_lds((const __attribute__((address_space(1))) unsigned int*)g,
                                   (__attribute__((address_space(3))) unsigned int*)l, 16, 0, 0);
}

// ---------------- prepass: cast x to fp16 ----------------
__global__ void cast_x(const float* __restrict__ x, short* __restrict__ xh) {
  int t = blockIdx.x * 256 + threadIdx.x;
  const float* s = x + (size_t)t * 8;
  float4 a = *(const float4*)s, b = *(const float4*)(s + 4);
  short8v h;
  h[0] = f2h(a.x); h[1] = f2h(a.y); h[2] = f2h(a.z); h[3] = f2h(a.w);
  h[4] = f2h(b.x); h[5] = f2h(b.y); h[6] = f2h(b.z); h[7] = f2h(b.w);
  *(short8v*)(xh + (size_t)t * 8) = h;
}

// ---------------- prepass: cast + transpose W -> Wt[n][k] fp16 ----------------
__global__ __launch_bounds__(256) void cast_wT(const float* __restrict__ Wq,
                                               const float* __restrict__ Wk,
                                               const float* __restrict__ Wv,
                                               const float* __restrict__ Wo,
                                               short* __restrict__ WTh) {
  __shared__ float T[64][68];
  const int z = blockIdx.z;
  const float* W = z == 0 ? Wq : z == 1 ? Wk : z == 2 ? Wv : Wo;
  short* oh = WTh + (size_t)z * 1048576;
  const int n0 = blockIdx.x * 64, k0 = blockIdx.y * 64;
  const int tid = threadIdx.x;
#pragma unroll
  for (int i = 0; i < 4; ++i) {
    int slot = tid + i * 256;
    int r = slot >> 4, c4 = (slot & 15) << 2;
    *(float4*)&T[r][c4] = *(const float4*)(W + (size_t)(k0 + r) * Cc + n0 + c4);
  }
  __syncthreads();
#pragma unroll
  for (int i = 0; i < 2; ++i) {
    int slot = tid + i * 256;
    int nl = slot >> 3, ks = (slot & 7) << 3;
    short8v h;
#pragma unroll
    for (int e = 0; e < 8; ++e) h[e] = f2h(T[ks + e][nl]);
    *(short8v*)(oh + (size_t)(n0 + nl) * Cc + k0 + ks) = h;
  }
}

// ================= 128x128 fp16 GEMM core (single-pass MFMA) =================
__device__ __forceinline__ void core128h(const short* __restrict__ Ah,
                                         const short* __restrict__ Bh,
                                         short* AhL, short* BhL,
                                         int row0, int col0, int wv, int lane, f32x4 acc[4][4]) {
  const int l15 = lane & 15, g = lane >> 4;
  const int wr = wv >> 1, wc = wv & 1;

  const int srow0 = wv * 32 + (lane >> 2);
  const int srow1 = srow0 + 16;
  const int sch0 = ((lane & 3) ^ ((lane >> 2) & 3)) << 3;
  const size_t aoff0 = (size_t)(row0 + srow0) * Cc + sch0;
  const size_t aoff1 = (size_t)(row0 + srow1) * Cc + sch0;
  const size_t boff0 = (size_t)(col0 + srow0) * Cc + sch0;
  const size_t boff1 = (size_t)(col0 + srow1) * Cc + sch0;
  short* dA0 = AhL + wv * 1024;  short* dA1 = dA0 + 512;
  short* dB0 = BhL + wv * 1024;  short* dB1 = dB0 + 512;

  int aL[4], bL[4];
#pragma unroll
  for (int m = 0; m < 4; ++m) aL[m] = (wr * 64 + m * 16 + l15) * 32 + ((g ^ (l15 & 3)) << 3);
#pragma unroll
  for (int n = 0; n < 4; ++n) bL[n] = (wc * 64 + n * 16 + l15) * 32 + ((g ^ (l15 & 3)) << 3);

  for (int k0 = 0; k0 < Cc; k0 += 32) {
    __syncthreads();
    gll16(Ah + aoff0 + k0, dA0);
    gll16(Ah + aoff1 + k0, dA1);
    gll16(Bh + boff0 + k0, dB0);
    gll16(Bh + boff1 + k0, dB1);
    __syncthreads();
    half8v a[4], b[4];
#pragma unroll
    for (int m = 0; m < 4; ++m) a[m] = __builtin_bit_cast(half8v, *(short8v*)&AhL[aL[m]]);
#pragma unroll
    for (int n = 0; n < 4; ++n) b[n] = __builtin_bit_cast(half8v, *(short8v*)&BhL[bL[n]]);
#pragma unroll
    for (int m = 0; m < 4; ++m)
#pragma unroll
      for (int n = 0; n < 4; ++n)
        acc[m][n] = __builtin_amdgcn_mfma_f32_16x16x32_f16(a[m], b[n], acc[m][n], 0, 0, 0);
  }
}

// ---------------- QKV projection GEMM (fp16), rope fused, V transposed ----------------
__global__ __launch_bounds__(256, 3) void gemm_qkv(const short* __restrict__ xh,
                                                   const short* __restrict__ WTh,
                                                   const float* __restrict__ bq,
                                                   const float* __restrict__ bk,
                                                   const float* __restrict__ bv,
                                                   short* __restrict__ qb,
                                                   short* __restrict__ kb,
                                                   short* __restrict__ vb) {
  __shared__ short AhL[4096], BhL[4096];
  const int mode = blockIdx.y;
  const short* Bh = WTh + (size_t)mode * 1048576;
  const float* bias = mode == 0 ? bq : mode == 1 ? bk : bv;
  short* Y = mode == 0 ? qb : mode == 1 ? kb : vb;

  const int bid = blockIdx.x;
  const int nid = ((bid & 7) << 5) | (bid >> 3);
  const int row0 = (nid >> 3) * 128, col0 = (nid & 7) * 128;
  const int lane = threadIdx.x & 63, wv = threadIdx.x >> 6;
  const int l15 = lane & 15, g = lane >> 4;
  const int wr = wv >> 1, wc = wv & 1;

  f32x4 acc[4][4];
#pragma unroll
  for (int m = 0; m < 4; ++m)
#pragma unroll
    for (int n = 0; n < 4; ++n) acc[m][n] = (f32x4){0.f, 0.f, 0.f, 0.f};

  core128h(xh, Bh, AhL, BhL, row0, col0, wv, lane, acc);

  const int cbase = col0 + wc * 64;
  const int h = cbase >> 6;
  if (mode < 2) {
    const float scale = (mode == 0) ? 0.18033688f : 1.0f;   // 1/8 * log2(e) folded for Q
#pragma unroll
    for (int n = 0; n < 2; ++n) {
      const int d = n * 16 + l15;
      const float b0 = bias[cbase + d], b1 = bias[cbase + d + 32];
      const float inv = exp2f(-(float)d * (13.2877123795494f / 32.f));
#pragma unroll
      for (int m = 0; m < 4; ++m)
#pragma unroll
        for (int rr = 0; rr < 4; ++rr) {
          int R = row0 + wr * 64 + m * 16 + g * 4 + rr;
          int bI = R >> 11, t = R & (Tt - 1);
          float sn, cs;
          sincosf((float)t * inv, &sn, &cs);
          float v0 = acc[m][n][rr] + b0, v1 = acc[m][n + 2][rr] + b1;
          size_t base = (((size_t)(bI * Hh + h) * Tt + t) << 6) + d;
          Y[base]      = f2h((v0 * cs - v1 * sn) * scale);
          Y[base + 32] = f2h((v1 * cs + v0 * sn) * scale);
        }
    }
  } else {
    // V: write transposed [B,H,D,T] fp16
#pragma unroll
    for (int n = 0; n < 2; ++n) {
      const int d = n * 16 + l15;
      const float b0 = bias[cbase + d], b1 = bias[cbase + d + 32];
#pragma unroll
      for (int m = 0; m < 4; ++m) {
        int R = row0 + wr * 64 + m * 16 + g * 4;
        int bI = R >> 11, t = R & (Tt - 1);
        short4v s0, s1;
#pragma unroll
        for (int rr = 0; rr < 4; ++rr) {
          s0[rr] = f2h(acc[m][n][rr] + b0);
          s1[rr] = f2h(acc[m][n + 2][rr] + b1);
        }
        size_t base = ((size_t)(bI * Hh + h) * Dd);
        *(short4v*)(Y + (base + d) * Tt + t)      = s0;
        *(short4v*)(Y + (base + d + 32) * Tt + t) = s1;
      }
    }
  }
}

// ---------------- final output GEMM (fp16 core, fp32 out) ----------------
__global__ __launch_bounds__(256, 3) void gemm_out(const short* __restrict__ ah,
                                                   const short* __restrict__ WTo,
                                                   const float* __restrict__ bias,
                                                   float* __restrict__ Y) {
  __shared__ short AhL[4096], BhL[4096];
  const int bid = blockIdx.x;
  const int nid = ((bid & 7) << 5) | (bid >> 3);
  const int row0 = (nid >> 3) * 128, col0 = (nid & 7) * 128;
  const int lane = threadIdx.x & 63, wv = threadIdx.x >> 6;
  const int l15 = lane & 15, g = lane >> 4;
  const int wr = wv >> 1, wc = wv & 1;

  f32x4 acc[4][4];
#pragma unroll
  for (int m = 0; m < 4; ++m)
#pragma unroll
    for (int n = 0; n < 4; ++n) acc[m][n] = (f32x4){0.f, 0.f, 0.f, 0.f};

  core128h(ah, WTo, AhL, BhL, row0, col0, wv, lane, acc);

  const int cbase = col0 + wc * 64;
#pragma unroll
  for (int n = 0; n < 2; ++n) {
    const int ccol = cbase + n * 16 + l15;
    const float b0 = bias[ccol], b1 = bias[ccol + 32];
#pragma unroll
    for (int m = 0; m < 4; ++m)
#pragma unroll
      for (int rr = 0; rr < 4; ++rr) {
        int R = row0 + wr * 64 + m * 16 + g * 4 + rr;
        Y[(size_t)R * Cc + ccol]      = acc[m][n][rr] + b0;
        Y[(size_t)R * Cc + ccol + 32] = acc[m][n + 2][rr] + b1;
      }
  }
}

// ================= MFMA flash attention v7 (r6 structure, fp16, balanced jobs) ====
// Job table per bh: heavy q-tiles (Q<=10, nch 40..64) split into 2 key-halves;
// light tiles (Q>=11) unsplit. 27 jobs/bh, lengths 20..36 chunks (vs 17..64),
// sorted heavy-first. Grid 8 xcd x 4 bh x 27 = 864 blocks, 4 waves each.
// LDS: K via global_load_lds + XOR swizzle; V^T conflict-free; dbuf, 1 barrier/chunk.
static __device__ const int JQ[27] = {11, 0,0, 1,1, 2,2, 3,3, 4,4, 12, 5,5,
                                      6,6, 13, 7,7, 8,8, 14, 9,9, 15, 10,10};
static __device__ const int JK[27] = {0, 0,1, 0,1, 0,1, 0,1, 0,1, 0, 0,1,
                                      0,1, 0, 0,1, 0,1, 0, 0,1, 0, 0,1};

__global__ __launch_bounds__(256, 4) void attn_mfma(const short* __restrict__ q,
                                                    const short* __restrict__ k,
                                                    const short* __restrict__ vT,
                                                    short* __restrict__ ah,
                                                    float* __restrict__ yb,
                                                    float* __restrict__ side) {
  const int n = blockIdx.x;           // 864
  const int xcd = n & 7;
  const int t7 = n >> 3;              // 0..107
  const int bhj = t7 / 27;
  const int j = t7 - bhj * 27;
  const int bh = xcd * 4 + bhj;
  const int Q = JQ[j];
  const int kh = JK[j];
  const int split = (Q <= 10);
  const int q0 = Q * 128;

  const int tid = threadIdx.x;
  const int lane = tid & 63;
  const int wv = tid >> 6;
  const int l31 = lane & 31;
  const int hb = lane >> 5;
  const int qbase = q0 + wv * 32;
  const int tq = qbase + l31;

  const short* qgb = q + (size_t)bh * Tt * Dd;
  const short* kgb = k + (size_t)bh * Tt * Dd;
  const short* vgb = vT + (size_t)bh * Dd * Tt;

  // Q fragments: MFMA i covers dims 16i + 8hb..+7 (scale*log2e folded)
  const short* qp = qgb + (size_t)tq * Dd + 8 * hb;
  half8v qf[4];
#pragma unroll
  for (int i = 0; i < 4; ++i) qf[i] = __builtin_bit_cast(half8v, *(const short8v*)(qp + 16 * i));

  __shared__ short Klds[2][32 * 64];
  __shared__ short Vt[2][64 * 40];

  // K staging (gll): wave wv stages rows 8wv..8wv+7; phys chunk lane&7,
  // source log chunk (lane&7)^(row&7)
  const int r8 = lane >> 3;
  const size_t ksrc_off = (size_t)(wv * 8 + r8) * Dd + (((lane & 7) ^ r8) << 3);

  // V^T staging: thread = (key-pair kp, dim-block db) -> conflict-free writes
  const int kp = tid & 15;
  const int db = tid >> 4;
  const size_t vsrc_off = (size_t)l31 * Tt;  // unused helper; real below
  (void)vsrc_off;
  const size_t vls = (size_t)(4 * db) * Tt + 2 * kp;  // not used; clarity

  // K fragment read offsets
  int koff[4];
#pragma unroll
  for (int i = 0; i < 4; ++i) koff[i] = l31 * 64 + (((2 * i + hb) ^ (l31 & 7)) << 3);

  f32x16 oacc[2];
#pragma unroll
  for (int t = 0; t < 2; ++t)
#pragma unroll
    for (int r = 0; r < 16; ++r) oacc[t][r] = 0.f;
  float mrun = -1e30f, lrun = 0.f;

  const int cs0 = (q0 >= 512) ? (q0 - 511) : 0;
  const int cstart = cs0 & ~31;
  const int nch_b = (Tt - cstart) >> 5;
  const int lower = (nch_b + 1) >> 1;
  const int mystart = cstart + ((split && kh) ? (lower << 5) : 0);
  const int myn = split ? (kh ? nch_b - lower : lower) : nch_b;

  short4v va, vb2;
  // V source: key 2kp/2kp+1 of chunk, dims 4db..4db+3 -> vT[d][t]: 4 strided reads.
  // Load as 4 shorts per key via [B,H,D,T]: element (d, t) at vgb[d*Tt + t].
  // va[e] = V[4db+e][jt+2kp], vb2[e] = V[4db+e][jt+2kp+1]
#define LOADV(JT)                                                        \
  {                                                                      \
    const short* vsp = vgb + (size_t)(4 * db) * Tt + (JT) + 2 * kp;      \
    va[0] = vsp[0];        vb2[0] = vsp[1];                              \
    va[1] = vsp[Tt];       vb2[1] = vsp[Tt + 1];                         \
    va[2] = vsp[2 * Tt];   vb2[2] = vsp[2 * Tt + 1];                     \
    va[3] = vsp[3 * Tt];   vb2[3] = vsp[3 * Tt + 1];                     \
  }
#define WRITEV(BUF)                                                      \
  {                                                                      \
    _Pragma("unroll")                                                    \
    for (int e = 0; e < 4; ++e) {                                        \
      unsigned w = (unsigned)(unsigned short)va[e] |                     \
                   ((unsigned)(unsigned short)vb2[e] << 16);             \
      *(unsigned*)&Vt[BUF][(4 * db + e) * 40 + 2 * kp] = w;              \
    }                                                                    \
  }

  // ---- prologue ----
  gll16(kgb + (size_t)mystart * Dd + ksrc_off, &Klds[0][wv * 512]);
  LOADV(mystart);
  WRITEV(0);
  if (myn > 1) LOADV(mystart + 32);
  __syncthreads();

  for (int ci = 0; ci < myn; ++ci) {
    const int jt = mystart + (ci << 5);
    const int cur = ci & 1;

    if (ci + 1 < myn) {
      gll16(kgb + (size_t)(jt + 32) * Dd + ksrc_off, &Klds[cur ^ 1][wv * 512]);
      WRITEV(cur ^ 1);
      if (ci + 2 < myn) LOADV(jt + 64);
    }

    if (jt + 32 > qbase - 511) {
      const short* kbuf = &Klds[cur][0];
      f32x16 se;
#pragma unroll
      for (int r = 0; r < 16; ++r) se[r] = 0.f;
#pragma unroll
      for (int i = 0; i < 4; ++i) {
        half8v kf = __builtin_bit_cast(half8v, *(short8v*)&kbuf[koff[i]]);
        se = __builtin_amdgcn_mfma_f32_32x32x16_f16(kf, qf[i], se, 0, 0, 0);
      }

      if (jt < qbase - 480) {   // boundary: window mask
        int th = tq - 511 - jt;
#pragma unroll
        for (int r = 0; r < 16; ++r) {
          int row = (r & 3) + 8 * (r >> 2) + 4 * hb;
          if (row < th) se[r] = -1e30f;
        }
      }

      float x0 = fmaxf(se[0], se[1]),   x1 = fmaxf(se[2], se[3]);
      float x2 = fmaxf(se[4], se[5]),   x3 = fmaxf(se[6], se[7]);
      float x4 = fmaxf(se[8], se[9]),   x5 = fmaxf(se[10], se[11]);
      float x6 = fmaxf(se[12], se[13]), x7 = fmaxf(se[14], se[15]);
      x0 = fmaxf(x0, x1); x2 = fmaxf(x2, x3); x4 = fmaxf(x4, x5); x6 = fmaxf(x6, x7);
      float cmax = fmaxf(fmaxf(x0, x2), fmaxf(x4, x6));
      cmax = fmaxf(cmax, __shfl_xor(cmax, 32));

      if (!__all(cmax <= mrun + 8.0f)) {
        float mnew = fmaxf(fmaxf(mrun, cmax), -1e29f);
        float fac = exp2f(mrun - mnew);
        lrun *= fac;
#pragma unroll
        for (int t = 0; t < 2; ++t)
#pragma unroll
          for (int r = 0; r < 16; ++r) oacc[t][r] *= fac;
        mrun = mnew;
      }

      float p[16], psum = 0.f;
#pragma unroll
      for (int r = 0; r < 16; ++r) { p[r] = exp2f(se[r] - mrun); psum += p[r]; }
      psum += __shfl_xor(psum, 32);
      lrun += psum;

      // pack p pairs to fp16 (1 op per pair) + half-wave exchange
      unsigned pk[8], pw[8];
#pragma unroll
      for (int i = 0; i < 8; ++i)
        pk[i] = __builtin_bit_cast(unsigned, __builtin_amdgcn_cvt_pkrtz(p[2 * i], p[2 * i + 1]));
#pragma unroll
      for (int i = 0; i < 8; ++i) pw[i] = __shfl_xor(pk[i], 32);

      uint4v f0, f1;
      f0[0] = hb ? pw[2] : pk[0];
      f0[1] = hb ? pw[3] : pk[1];
      f0[2] = hb ? pk[2] : pw[0];
      f0[3] = hb ? pk[3] : pw[1];
      f1[0] = hb ? pw[6] : pk[4];
      f1[1] = hb ? pw[7] : pk[5];
      f1[2] = hb ? pk[6] : pw[4];
      f1[3] = hb ? pk[7] : pw[5];
      half8v pf0 = __builtin_bit_cast(half8v, f0);
      half8v pf1 = __builtin_bit_cast(half8v, f1);

#pragma unroll
      for (int t = 0; t < 2; ++t) {
        const int vrow = (32 * t + l31) * 40;
        half8v v0 = __builtin_bit_cast(half8v, *(short8v*)&Vt[cur][vrow + (hb << 3)]);
        half8v v1 = __builtin_bit_cast(half8v, *(short8v*)&Vt[cur][vrow + ((2 + hb) << 3)]);
        oacc[t] = __builtin_amdgcn_mfma_f32_32x32x16_f16(v0, pf0, oacc[t], 0, 0, 0);
        oacc[t] = __builtin_amdgcn_mfma_f32_32x32x16_f16(v1, pf1, oacc[t], 0, 0, 0);
      }
    }
    __syncthreads();
  }

  // ---- epilogue ----
  const float invl = 1.f / lrun;
  const int row = bh * Tt + tq;
  if (split && hb == 0) {
    side[(kh << 17) + row]         = mrun;
    side[(kh << 17) + 65536 + row] = lrun;
  }
  const int bI = bh >> 4, hd = bh & 15;
  if (!split || kh == 0) {
    short* op = ah + ((size_t)(bI * Tt + tq)) * Cc + hd * Dd;
#pragma unroll
    for (int t = 0; t < 2; ++t)
#pragma unroll
      for (int rq = 0; rq < 4; ++rq) {
        short4v hv;
#pragma unroll
        for (int rr = 0; rr < 4; ++rr) hv[rr] = f2h(oacc[t][4 * rq + rr] * invl);
        *(short4v*)(op + 32 * t + 8 * rq + 4 * hb) = hv;
      }
  } else {
    float* yp = yb + (size_t)row * 64;
#pragma unroll
    for (int t = 0; t < 2; ++t)
#pragma unroll
      for (int rq = 0; rq < 4; ++rq) {
        f32x4 o4;
#pragma unroll
        for (int rr = 0; rr < 4; ++rr) o4[rr] = oacc[t][4 * rq + rr] * invl;
        *(f32x4*)(yp + 32 * t + 8 * rq + 4 * hb) = o4;
      }
  }
}

// ---------------- merge the two key-halves for split tiles (tq < 1408) ----------------
__global__ __launch_bounds__(256) void attn_merge(short* __restrict__ ah,
                                                  const float* __restrict__ yb,
                                                  const float* __restrict__ side) {
  const int bh = blockIdx.y;
  const int idx = blockIdx.x * 256 + threadIdx.x;   // [0, 5632)
  const int tq = idx >> 2;                           // [0, 1408)
  const int qd = (idx & 3) << 4;
  const int row = bh * Tt + tq;
  const float m0 = side[row],          l0 = side[65536 + row];
  const float m1 = side[131072 + row], l1 = side[196608 + row];
  const float m = fmaxf(m0, m1);
  const float w0 = exp2f(m0 - m) * l0;
  const float w1 = exp2f(m1 - m) * l1;
  const float inv = 1.f / (w0 + w1);
  const float a0 = w0 * inv, a1 = w1 * inv;

  const int bI = bh >> 4, hd = bh & 15;
  short* op = ah + ((size_t)(bI * Tt + tq)) * Cc + hd * Dd + qd;
  const float* yp = yb + (size_t)row * 64 + qd;

  short8v h0 = *(short8v*)op, h1 = *(short8v*)(op + 8);
  short8v o0, o1;
#pragma unroll
  for (int e = 0; e < 8; ++e) o0[e] = f2h(a0 * h2f(h0[e]) + a1 * yp[e]);
#pragma unroll
  for (int e = 0; e < 8; ++e) o1[e] = f2h(a0 * h2f(h1[e]) + a1 * yp[8 + e]);
  *(short8v*)op = o0;
  *(short8v*)(op + 8) = o1;
}

extern "C" void kernel_launch(void* const* d_in, const int* in_sizes, int n_in,
                              void* d_out, int out_size, void* d_ws, size_t ws_size,
                              hipStream_t stream) {
  const float* x  = (const float*)d_in[0];
  const float* Wq = (const float*)d_in[1];
  const float* bq = (const float*)d_in[2];
  const float* Wk = (const float*)d_in[3];
  const float* bk = (const float*)d_in[4];
  const float* Wv = (const float*)d_in[5];
  const float* bv = (const float*)d_in[6];
  const float* Wo = (const float*)d_in[7];
  const float* bo = (const float*)d_in[8];

  short* ws16 = (short*)d_ws;
  short* xh  = ws16;                  // 8MB fp16 x
  short* WTh = ws16 + 4194304;        // 8MB: Wq,Wk,Wv,Wo transposed fp16
  short* qb  = ws16 + 8388608;        // 8MB fp16 [B,H,T,D]
  short* kb  = ws16 + 12582912;       // 8MB fp16 [B,H,T,D]
  short* vb  = ws16 + 16777216;       // 8MB fp16 [B,H,D,T] (V transposed)
  short* ah  = ws16 + 20971520;       // 8MB fp16 attn out [B,T,C]
  float* yb   = (float*)(ws16 + 25165824);  // 16.78MB fp32 kh=1 partials [65536][64]
  float* side = yb + 4194304;               // 1MB: [kh][m|l][65536]

  cast_x<<<2048, 256, 0, stream>>>(x, xh);
  cast_wT<<<dim3(16, 16, 4), 256, 0, stream>>>(Wq, Wk, Wv, Wo, WTh);

  gemm_qkv<<<dim3(256, 3), 256, 0, stream>>>(xh, WTh, bq, bk, bv, qb, kb, vb);

  attn_mfma<<<864, 256, 0, stream>>>(qb, kb, vb, ah, yb, side);
  attn_merge<<<dim3(22, 32), 256, 0, stream>>>(ah, yb, side);

  gemm_out<<<256, 256, 0, stream>>>(ah, WTh + 3 * 1048576, bo, (float*)d_out);
}